// Round 2
// baseline (5781.073 us; speedup 1.0000x reference)
//
#include <hip/hip_runtime.h>

#define B_  128
#define S_  256
#define E_  300
#define EP_ 320
#define H_  512
#define G_  2048   // 4*H
#define D1_ 1024   // 2*H

typedef _Float16 f16;
typedef __attribute__((ext_vector_type(8))) _Float16 f16x8;
typedef __attribute__((ext_vector_type(4))) float    f32x4;

__device__ __forceinline__ float sigf(float x){ return 1.f/(1.f + __expf(-x)); }
__device__ __forceinline__ float tanhf_(float x){
  float e = __expf(-2.f*fabsf(x));
  float t = (1.f - e)/(1.f + e);
  return x < 0.f ? -t : t;
}

// ---------------- conversion / setup kernels ----------------

__global__ void k_f32_to_f16(const float* __restrict__ s, f16* __restrict__ d, int n){
  int i = blockIdx.x*blockDim.x + threadIdx.x;
  if (i < n) d[i] = (f16)s[i];
}

__global__ void k_pad_w(const float* __restrict__ s, f16* __restrict__ d, int rows, int ks, int kd){
  int i = blockIdx.x*blockDim.x + threadIdx.x;
  if (i >= rows*kd) return;
  int r = i/kd, k = i - r*kd;
  d[i] = (k < ks) ? (f16)s[(size_t)r*ks + k] : (f16)0.f;
}

// xc[(tc*B+b)*EP + e] = x[b][t0+tc][e], zero-padded E->EP, for tc in [0,CHn)
__global__ void k_conv_chunk(const float* __restrict__ x, f16* __restrict__ xc, int t0, int CHn){
  int i = blockIdx.x*blockDim.x + threadIdx.x;
  if (i >= CHn*B_*EP_) return;
  int r = i/EP_, e = i - r*EP_;
  int tc = r >> 7;      // r / 128
  int b  = r & 127;
  xc[i] = (e < E_) ? (f16)x[((size_t)b*S_ + t0 + tc)*E_ + e] : (f16)0.f;
}

__global__ void k_bias(const float* __restrict__ a, const float* __restrict__ b,
                       float* __restrict__ d, int n){
  int i = blockIdx.x*blockDim.x + threadIdx.x;
  if (i < n) d[i] = a[i] + b[i];
}

__global__ void k_len(const float* __restrict__ x, int* __restrict__ len){
  int b = threadIdx.x;
  if (b < B_){
    int v = (int)x[((size_t)b*S_ + (S_-1))*E_];
    len[b] = v > S_ ? S_ : v;
  }
}

__global__ void k_init(f16* hf, f16* hr, f16* h1, float* cf, float* cr, float* c1){
  int i = blockIdx.x*blockDim.x + threadIdx.x;
  if (i < B_*H_){
    hf[i] = (f16)1.f; hr[i] = (f16)1.f; h1[i] = (f16)1.f;
    cf[i] = 1.f; cr[i] = 1.f; c1[i] = 1.f;
  }
}

// ---------------- GEMM: C[M,N] = A[M,K] @ B[N,K]^T + bias, f16 in/out, fp32 acc ----------------

__global__ __launch_bounds__(256) void k_gemm_bt(
    const f16* __restrict__ A, const f16* __restrict__ Bm,
    f16* __restrict__ C, const float* __restrict__ bias,
    int M, int N, int K)
{
  __shared__ f16 As[64*40];
  __shared__ f16 Bs[64*40];
  const int m0 = blockIdx.x*64, n0 = blockIdx.y*64;
  const int tid = threadIdx.x;
  const int w = tid>>6, lane = tid&63, quad = lane>>4, l16 = lane&15;
  const int wm = (w&1)*32, wn = (w>>1)*32;
  const int lr = tid>>2, lc = (tid&3)*8;
  const f16* Ap = A + (size_t)(m0+lr)*K + lc;
  const f16* Bp = Bm + (size_t)(n0+lr)*K + lc;
  f32x4 z4 = {0.f,0.f,0.f,0.f};
  f32x4 acc[2][2] = {{z4,z4},{z4,z4}};
  for (int k0 = 0; k0 < K; k0 += 32){
    *(uint4*)&As[lr*40+lc] = *(const uint4*)(Ap + k0);
    *(uint4*)&Bs[lr*40+lc] = *(const uint4*)(Bp + k0);
    __syncthreads();
    f16x8 a0 = *(const f16x8*)&As[(wm+l16)*40 + quad*8];
    f16x8 a1 = *(const f16x8*)&As[(wm+16+l16)*40 + quad*8];
    f16x8 b0 = *(const f16x8*)&Bs[(wn+l16)*40 + quad*8];
    f16x8 b1 = *(const f16x8*)&Bs[(wn+16+l16)*40 + quad*8];
    acc[0][0] = __builtin_amdgcn_mfma_f32_16x16x32_f16(a0,b0,acc[0][0],0,0,0);
    acc[0][1] = __builtin_amdgcn_mfma_f32_16x16x32_f16(a0,b1,acc[0][1],0,0,0);
    acc[1][0] = __builtin_amdgcn_mfma_f32_16x16x32_f16(a1,b0,acc[1][0],0,0,0);
    acc[1][1] = __builtin_amdgcn_mfma_f32_16x16x32_f16(a1,b1,acc[1][1],0,0,0);
    __syncthreads();
  }
#pragma unroll
  for (int mi = 0; mi < 2; ++mi)
#pragma unroll
    for (int ni = 0; ni < 2; ++ni){
      int col = n0 + wn + ni*16 + l16;
      float bz = bias[col];
#pragma unroll
      for (int r = 0; r < 4; ++r){
        int row = m0 + wm + mi*16 + quad*4 + r;
        C[(size_t)row*N + col] = (f16)(acc[mi][ni][r] + bz);
      }
    }
}

// ---------------- recurrent step kernel ----------------
// grid (2, 32, ndir), block 256 (4 waves).
// Each block: 64 batch rows (4 waves x 16) x 16 hidden units x 4 gates.
// W_hh rows (4 gates x 16 hidden) staged in 32KB LDS in two K-halves,
// XOR-swizzled on 16B units.
// z = Zchunk[zrow] + h_in @ Whh^T ; gates ; masked update -> h_out (dbuf), c in place.

__global__ __launch_bounds__(256) void k_step(
    const f16* __restrict__ Zf, const f16* __restrict__ Zr,
    const f16* __restrict__ Wf, const f16* __restrict__ Wr,
    const f16* __restrict__ hinf, f16* __restrict__ houtf,
    const f16* __restrict__ hinr, f16* __restrict__ houtr,
    float* __restrict__ cfp, float* __restrict__ crp,
    f16* __restrict__ outcat, float* __restrict__ hfinal,
    const int* __restrict__ len,
    int tf, int tr, int rowf, int rowr, int writeFinal)
{
  __shared__ f16 Wl[64*256];   // 32 KB
  const int dir = blockIdx.z;
  const f16* Zin = dir ? Zr : Zf;
  const f16* Whh = dir ? Wr : Wf;
  const f16* hin = dir ? hinr : hinf;
  f16* hout      = dir ? houtr : houtf;
  float* cbuf    = dir ? crp : cfp;
  const int t    = dir ? tr : tf;
  const int zrow = dir ? rowr : rowf;
  const int tid = threadIdx.x;
  const int w = tid>>6, lane = tid&63, quad = lane>>4, l16 = lane&15;
  const int j0 = blockIdx.y*16;          // hidden base (16 units/block)
  const int m0 = blockIdx.x*64 + w*16;   // batch base per wave

  f32x4 z4 = {0.f,0.f,0.f,0.f};
  f32x4 acc[4] = {z4,z4,z4,z4};
  const f16* hrow = hin + (size_t)(m0 + l16)*H_ + quad*8;

#pragma unroll
  for (int half = 0; half < 2; ++half){
    // cooperative stage: 64 rows (4 gates x 16 hidden) x 256 k (one K-half)
    for (int u = tid; u < 2048; u += 256){
      int lrr = u >> 5;         // local row 0..63
      int uc  = u & 31;         // 16B-unit within half-row
      int g = lrr >> 4, i = lrr & 15;
      const f16* src = Whh + ((size_t)(g*H_ + j0 + i))*H_ + half*256 + uc*8;
      *(uint4*)&Wl[lrr*256 + (uc ^ (i & 7))*8] = *(const uint4*)src;
    }
    __syncthreads();
#pragma unroll
    for (int k0 = 0; k0 < 256; k0 += 32){
      f16x8 a = *(const f16x8*)(hrow + half*256 + k0);
      int uq = (k0 >> 3) + quad;   // 0..31
#pragma unroll
      for (int g = 0; g < 4; ++g){
        int lrr = g*16 + l16;
        f16x8 b = *(const f16x8*)&Wl[lrr*256 + ((uq ^ (l16 & 7)))*8];
        acc[g] = __builtin_amdgcn_mfma_f32_16x16x32_f16(a, b, acc[g], 0,0,0);
      }
    }
    __syncthreads();
  }

  const int j = j0 + l16;
#pragma unroll
  for (int r = 0; r < 4; ++r){
    int m = m0 + quad*4 + r;
    size_t zb = ((size_t)zrow*B_ + m)*G_;
    float zi = acc[0][r] + (float)Zin[zb          + j];
    float zf = acc[1][r] + (float)Zin[zb +   H_  + j];
    float zg = acc[2][r] + (float)Zin[zb + 2*H_  + j];
    float zo = acc[3][r] + (float)Zin[zb + 3*H_  + j];
    float ig = sigf(zi), fg = sigf(zf), gg = tanhf_(zg), og = sigf(zo);
    size_t hx = (size_t)m*H_ + j;
    float cold = cbuf[hx];
    float cnew = fg*cold + ig*gg;
    float hnew = og*tanhf_(cnew);
    bool mk = t < len[m];
    float hsel = mk ? hnew : (float)hin[hx];
    float csel = mk ? cnew : cold;
    hout[hx] = (f16)hsel;
    cbuf[hx] = csel;
    if (outcat) outcat[((size_t)t*B_ + m)*D1_ + dir*H_ + j] = (f16)hsel;
    if (hfinal && writeFinal) hfinal[hx] = hsel;
  }
}

// ---------------- epilogue: folded FC ----------------

__global__ void k_fold(const float* __restrict__ fc1w, const float* __restrict__ fc1b,
                       const float* __restrict__ fcw,  const float* __restrict__ fcb,
                       float* __restrict__ Mf, float* __restrict__ bf){
  int i = blockIdx.x*blockDim.x + threadIdx.x;
  if (i >= 1024) return;
  int o = i >> 9, h = i & 511;
  float s = 0.f;
  for (int jj = 0; jj < 512; ++jj) s += fcw[o*512 + jj] * fc1w[jj*512 + h];
  Mf[o*512 + h] = s;
  if (h == 0){
    float sb = fcb[o];
    for (int jj = 0; jj < 512; ++jj) sb += fcw[o*512 + jj] * fc1b[jj];
    bf[o] = sb;
  }
}

__global__ void k_final(const float* __restrict__ h1f, const float* __restrict__ Mf,
                        const float* __restrict__ bf, float* __restrict__ out){
  int i = threadIdx.x;
  if (i >= 256) return;
  int b = i >> 1, o = i & 1;
  float s = bf[o];
  const float* hp = h1f + (size_t)b*512;
  const float* mp = Mf + (size_t)o*512;
  for (int h = 0; h < 512; ++h) s += hp[h]*mp[h];
  out[b*2 + o] = s;
}

// ---------------- host ----------------

extern "C" void kernel_launch(void* const* d_in, const int* in_sizes, int n_in,
                              void* d_out, int out_size, void* d_ws, size_t ws_size,
                              hipStream_t stream)
{
  const float* x     = (const float*)d_in[0];
  const float* wih0f = (const float*)d_in[1];
  const float* whh0f = (const float*)d_in[2];
  const float* bih0f = (const float*)d_in[3];
  const float* bhh0f = (const float*)d_in[4];
  const float* wih0r = (const float*)d_in[5];
  const float* whh0r = (const float*)d_in[6];
  const float* bih0r = (const float*)d_in[7];
  const float* bhh0r = (const float*)d_in[8];
  // d_in[9..12] = layer1 forward: dead code (only hT_r of layer1 is used)
  const float* wih1r = (const float*)d_in[13];
  const float* whh1r = (const float*)d_in[14];
  const float* bih1r = (const float*)d_in[15];
  const float* bhh1r = (const float*)d_in[16];
  const float* fc1w  = (const float*)d_in[17];
  const float* fc1b  = (const float*)d_in[18];
  const float* fcw   = (const float*)d_in[19];
  const float* fcb   = (const float*)d_in[20];
  float* out = (float*)d_out;

  // ---- adaptive time-chunk: fit workspace ----
  // fixed: weights ~13.1MB + outcat 64MB + states ~1.8MB; per-CH: 2*xc + 2*Zc
  const size_t fixed_bytes =
      (size_t)B_*S_*D1_*2                        // outcat
    + 2*(size_t)G_*EP_*2 + 3*(size_t)G_*H_*2 + (size_t)G_*D1_*2  // weights
    + 3*G_*4 + B_*4                               // biases, len
    + 3*(size_t)2*B_*H_*2 + 4*(size_t)B_*H_*4     // h dbufs, c bufs + h1f
    + 2*512*4 + 256 + 64*256;                     // Mf, bf, align slack
  int CH = 8;
  for (int c = 64; c >= 8; c >>= 1){
    size_t need = fixed_bytes + (size_t)c*(2*(size_t)B_*EP_*2 + 2*(size_t)B_*G_*2);
    if (need <= ws_size){ CH = c; break; }
  }
  const int NC = S_/CH;

  char* p = (char*)d_ws;
  auto alloc = [&](size_t bytes)->char*{
    char* r = p; p += (bytes + 255) & ~(size_t)255; return r;
  };
  f16* w0fp   = (f16*)alloc((size_t)G_*EP_*2);
  f16* w0rp   = (f16*)alloc((size_t)G_*EP_*2);
  f16* whf    = (f16*)alloc((size_t)G_*H_*2);
  f16* whr    = (f16*)alloc((size_t)G_*H_*2);
  f16* w1h    = (f16*)alloc((size_t)G_*H_*2);
  f16* w1i    = (f16*)alloc((size_t)G_*D1_*2);
  float* bs0f = (float*)alloc(G_*4);
  float* bs0r = (float*)alloc(G_*4);
  float* bs1r = (float*)alloc(G_*4);
  int*   len  = (int*)alloc(B_*4);
  f16* outcat = (f16*)alloc((size_t)S_*B_*D1_*2);   // 64 MB
  f16* hf     = (f16*)alloc((size_t)2*B_*H_*2);
  f16* hr     = (f16*)alloc((size_t)2*B_*H_*2);
  f16* h1     = (f16*)alloc((size_t)2*B_*H_*2);
  float* cf   = (float*)alloc((size_t)B_*H_*4);
  float* cr   = (float*)alloc((size_t)B_*H_*4);
  float* c1   = (float*)alloc((size_t)B_*H_*4);
  float* h1f  = (float*)alloc((size_t)B_*H_*4);
  float* Mf   = (float*)alloc(2*512*4);
  float* bf   = (float*)alloc(256);
  f16* xcf    = (f16*)alloc((size_t)CH*B_*EP_*2);
  f16* xcr    = (f16*)alloc((size_t)CH*B_*EP_*2);
  f16* Zfc    = (f16*)alloc((size_t)CH*B_*G_*2);
  f16* Zrc    = (f16*)alloc((size_t)CH*B_*G_*2);
  f16* Z1c    = Zfc;   // phase C reuses Zfc (phase A fully done by then)
  // NOTE: no early-return guard — if ws_size < need(CH=8) (~88MB) output will be
  // visibly garbage (non-zero), which is itself diagnostic.

  int n;
  n = G_*EP_;    k_pad_w<<<(n+255)/256, 256, 0, stream>>>(wih0f, w0fp, G_, E_, EP_);
                 k_pad_w<<<(n+255)/256, 256, 0, stream>>>(wih0r, w0rp, G_, E_, EP_);
  n = G_*H_;     k_f32_to_f16<<<(n+255)/256,256,0,stream>>>(whh0f, whf, n);
                 k_f32_to_f16<<<(n+255)/256,256,0,stream>>>(whh0r, whr, n);
                 k_f32_to_f16<<<(n+255)/256,256,0,stream>>>(whh1r, w1h, n);
  n = G_*D1_;    k_f32_to_f16<<<(n+255)/256,256,0,stream>>>(wih1r, w1i, n);
  k_bias<<<8,256,0,stream>>>(bih0f, bhh0f, bs0f, G_);
  k_bias<<<8,256,0,stream>>>(bih0r, bhh0r, bs0r, G_);
  k_bias<<<8,256,0,stream>>>(bih1r, bhh1r, bs1r, G_);
  k_len<<<1,128,0,stream>>>(x, len);
  n = B_*H_; k_init<<<(n+255)/256,256,0,stream>>>(hf, hr, h1, cf, cr, c1);
  k_fold<<<4,256,0,stream>>>(fc1w, fc1b, fcw, fcb, Mf, bf);

  const int HS = B_*H_;
  const int nconv = CH*B_*EP_;

  // ---- phase A: layer-0 fwd + rev, fused per step, Z in CH-sized chunks ----
  for (int cc = 0; cc < NC; ++cc){
    int t0f = cc*CH;             // fwd chunk covers t in [t0f, t0f+CH)
    int t0r = S_ - (cc+1)*CH;    // rev chunk covers t in [t0r, t0r+CH)
    k_conv_chunk<<<(nconv+255)/256, 256, 0, stream>>>(x, xcf, t0f, CH);
    k_conv_chunk<<<(nconv+255)/256, 256, 0, stream>>>(x, xcr, t0r, CH);
    k_gemm_bt<<<dim3(CH*2,32), 256, 0, stream>>>(xcf, w0fp, Zfc, bs0f, CH*B_, G_, EP_);
    k_gemm_bt<<<dim3(CH*2,32), 256, 0, stream>>>(xcr, w0rp, Zrc, bs0r, CH*B_, G_, EP_);
    for (int sl = 0; sl < CH; ++sl){
      int s = cc*CH + sl;
      int pa = s & 1;
      k_step<<<dim3(2,32,2), 256, 0, stream>>>(Zfc, Zrc, whf, whr,
          hf + pa*HS, hf + (1-pa)*HS, hr + pa*HS, hr + (1-pa)*HS,
          cf, cr, outcat, (float*)nullptr, len,
          /*tf=*/s, /*tr=*/S_-1-s, /*rowf=*/sl, /*rowr=*/CH-1-sl, 0);
    }
  }

  // ---- phase C: layer-1 reverse, Z1 chunks GEMM'd from outcat ----
  for (int cc = 0; cc < NC; ++cc){
    int t0 = S_ - (cc+1)*CH;     // chunk covers t in [t0, t0+CH), consumed descending
    k_gemm_bt<<<dim3(CH*2,32), 256, 0, stream>>>(outcat + (size_t)t0*B_*D1_, w1i, Z1c, bs1r, CH*B_, G_, D1_);
    for (int sl = 0; sl < CH; ++sl){
      int s = cc*CH + sl;
      int pa = s & 1;
      int t = S_-1-s;
      k_step<<<dim3(2,32,1), 256, 0, stream>>>(Z1c, (const f16*)nullptr, w1h, (const f16*)nullptr,
          h1 + pa*HS, h1 + (1-pa)*HS, (const f16*)nullptr, (f16*)nullptr,
          c1, (float*)nullptr, (f16*)nullptr, h1f, len,
          /*tf=*/t, /*tr=*/0, /*rowf=*/CH-1-sl, /*rowr=*/0, (s==S_-1)?1:0);
    }
  }

  k_final<<<1,256,0,stream>>>(h1f, Mf, bf, out);
}